// Round 14
// baseline (400.820 us; speedup 1.0000x reference)
//
#include <hip/hip_runtime.h>
#include <hip/hip_bf16.h>
#include <math.h>

#define NN   10000
#define EE   160000
#define CC   128
#define RBFD 20
#define HIDD 32
#define WND  384
#define MROW 1152   // 9*128 accumulator row: [m=0..8][c=0..127]

// Static device buffers (fully rewritten each call).
__device__ __align__(16) float g_proj[(size_t)NN * 64];   // 2.6 MB: Pi(32,+bs1)|Pj(32)
__device__ __align__(16) float g_accu[(size_t)NN * MROW]; // 46 MB, atomically accumulated
__device__ int g_deg[NN];
__device__ int g_offs[NN + 1];
__device__ int g_rel[EE];
__device__ int g_ord[EE];   // sorted row -> original edge

__device__ __forceinline__ float silu_f(float x) { return x / (1.f + __expf(-x)); }

// Zero g_deg and g_accu in one launch.
__global__ __launch_bounds__(256) void zero_kernel()
{
    int tid = blockIdx.x * 256 + threadIdx.x;
    if (tid < NN) g_deg[tid] = 0;
    float4* p = reinterpret_cast<float4*>(g_accu);
    float4 z = make_float4(0.f, 0.f, 0.f, 0.f);
    int n4 = NN * MROW / 4;
    for (int i = tid; i < n4; i += gridDim.x * 256) p[i] = z;
}

__global__ __launch_bounds__(256) void hist_kernel(const int* __restrict__ edge_index)
{
    int e = blockIdx.x * 256 + threadIdx.x;
    if (e < EE) g_rel[e] = atomicAdd(&g_deg[edge_index[e]], 1);
}

// Blocked scan: 256 threads x 40 items, one block.
__global__ __launch_bounds__(256) void scan_kernel()
{
    __shared__ int sP[256];
    int t = threadIdx.x;
    int lo = t * 40, hi = min(lo + 40, NN);
    int sum = 0;
    for (int i = lo; i < hi; ++i) sum += g_deg[i];
    sP[t] = sum;
    __syncthreads();
    for (int off = 1; off < 256; off <<= 1) {
        int v = (t >= off) ? sP[t - off] : 0;
        __syncthreads();
        sP[t] += v;
        __syncthreads();
    }
    int run = sP[t] - sum;   // exclusive prefix
    if (t == 0) g_offs[0] = 0;
    for (int i = lo; i < hi; ++i) { run += g_deg[i]; g_offs[i + 1] = run; }
}

__global__ __launch_bounds__(256) void perm_kernel(const int* __restrict__ edge_index)
{
    int e = blockIdx.x * 256 + threadIdx.x;
    if (e < EE) g_ord[g_offs[edge_index[e]] + g_rel[e]] = e;
}

// Per-node halves of MLP1: Pi = nf@Ws1[0:128]+bs1, Pj = nf@Ws1[128:256].
__global__ __launch_bounds__(64) void proj_kernel(
    const float* __restrict__ nf,
    const float* __restrict__ Ws1, const float* __restrict__ bs1)
{
    int n = blockIdx.x * 64 + threadIdx.x;
    if (n >= NN) return;
    float Pi[HIDD], Pj[HIDD];
    #pragma unroll
    for (int j = 0; j < HIDD; ++j) { Pi[j] = bs1[j]; Pj[j] = 0.f; }
    const float4* x4 = reinterpret_cast<const float4*>(nf + (size_t)n * CC);
    #pragma unroll 1
    for (int k4 = 0; k4 < CC / 4; ++k4) {
        float4 a = x4[k4];
        const float* wi = Ws1 + (4 * k4) * HIDD;
        const float* wj = Ws1 + (CC + 4 * k4) * HIDD;
        #pragma unroll
        for (int j = 0; j < HIDD; ++j) {
            Pi[j] = fmaf(a.x, wi[j], Pi[j]);
            Pi[j] = fmaf(a.y, wi[HIDD + j], Pi[j]);
            Pi[j] = fmaf(a.z, wi[2 * HIDD + j], Pi[j]);
            Pi[j] = fmaf(a.w, wi[3 * HIDD + j], Pi[j]);
            Pj[j] = fmaf(a.x, wj[j], Pj[j]);
            Pj[j] = fmaf(a.y, wj[HIDD + j], Pj[j]);
            Pj[j] = fmaf(a.z, wj[2 * HIDD + j], Pj[j]);
            Pj[j] = fmaf(a.w, wj[3 * HIDD + j], Pj[j]);
        }
    }
    float* o = g_proj + (size_t)n * 64;
    #pragma unroll
    for (int j = 0; j < HIDD; ++j) { o[j] = Pi[j]; o[HIDD + j] = Pj[j]; }
}

// One 64-col half-section: lane owns one column; weights in 64 VGPRs; streams
// 64 sorted edges (h via broadcast b128 from LDS), accumulates per-segment in
// registers, flushes wave-coalesced atomics into g_accu.
template<int K, int YB, int MOFF>
__device__ __forceinline__ void section_pass(
    int col, int xcol,
    const float* __restrict__ nf,
    const float* __restrict__ Ws2, const float* __restrict__ bs2,
    const float* __restrict__ Wr2, const float* __restrict__ br2,
    const float (*__restrict__ sH)[68], const float (*__restrict__ sY)[9],
    const int* __restrict__ sSrc, const int* __restrict__ sDst)
{
    float Wp[HIDD], Rp[HIDD];
    #pragma unroll
    for (int j = 0; j < HIDD; ++j) {
        Wp[j] = Ws2[j * WND + col];
        Rp[j] = Wr2[j * WND + col];
    }
    float bsv = bs2[col], brv = br2[col];

    float racc[K];
    #pragma unroll
    for (int k = 0; k < K; ++k) racc[k] = 0.f;
    int cur = sSrc[0];
    float xjn = nf[(size_t)sDst[0] * CC + xcol];

    #pragma unroll 2
    for (int ee = 0; ee < 64; ++ee) {
        int src = sSrc[ee];                       // broadcast -> wave-uniform
        if (src != cur) {
            float* ab = g_accu + (size_t)cur * MROW + MOFF + col % CC;
            #pragma unroll
            for (int k = 0; k < K; ++k) {
                unsafeAtomicAdd(ab + k * CC, racc[k]);
                racc[k] = 0.f;
            }
            cur = src;
        }
        float xj = xjn;
        xjn = nf[(size_t)sDst[(ee + 1) & 63] * CC + xcol];   // prefetch next
        float as = bsv, ar = brv;
        #pragma unroll
        for (int j4 = 0; j4 < 8; ++j4) {
            float4 hsv = *reinterpret_cast<const float4*>(&sH[ee][4 * j4]);
            float4 hrv = *reinterpret_cast<const float4*>(&sH[ee][32 + 4 * j4]);
            as = fmaf(hsv.x, Wp[4 * j4 + 0], as);
            as = fmaf(hsv.y, Wp[4 * j4 + 1], as);
            as = fmaf(hsv.z, Wp[4 * j4 + 2], as);
            as = fmaf(hsv.w, Wp[4 * j4 + 3], as);
            ar = fmaf(hrv.x, Rp[4 * j4 + 0], ar);
            ar = fmaf(hrv.y, Rp[4 * j4 + 1], ar);
            ar = fmaf(hrv.z, Rp[4 * j4 + 2], ar);
            ar = fmaf(hrv.w, Rp[4 * j4 + 3], ar);
        }
        float u = as * ar * xj;
        #pragma unroll
        for (int k = 0; k < K; ++k)
            racc[k] = fmaf(u, sY[ee][YB + k], racc[k]);
    }
    float* ab = g_accu + (size_t)cur * MROW + MOFF + col % CC;
    #pragma unroll
    for (int k = 0; k < K; ++k) unsafeAtomicAdd(ab + k * CC, racc[k]);
}

// Fused edge MLP2 + tensor-product message + segment-sum. 128-thr block =
// 2 waves sharing one 64-edge LDS tile; wave = 64-column half of each
// section. Prologue: wave 0 computes hs+metadata, wave 1 computes hr.
__global__ __launch_bounds__(128) void fused_kernel(
    const float* __restrict__ nf,
    const float* __restrict__ edge_attr,
    const float* __restrict__ edge_rsh,
    const int*   __restrict__ edge_index,
    const float* __restrict__ Ws2, const float* __restrict__ bs2,
    const float* __restrict__ Wr1, const float* __restrict__ br1,
    const float* __restrict__ Wr2, const float* __restrict__ br2)
{
    __shared__ float sH[64][68];   // 17.4 KB
    __shared__ float sY[64][9];    // 2.3 KB
    __shared__ int   sSrc[64], sDst[64];

    int h = threadIdx.x >> 6;      // wave id = column half
    int l = threadIdx.x & 63;
    int p = blockIdx.x * 64 + l;   // grid exact: EE/64
    int e = g_ord[p];
    int s = edge_index[e];
    int t = edge_index[EE + e];

    if (h == 0) {
        // ---- hs = silu(Pi[s] + Pj[t]) + metadata
        const float4* pi = reinterpret_cast<const float4*>(g_proj + (size_t)s * 64);
        const float4* pj = reinterpret_cast<const float4*>(g_proj + (size_t)t * 64 + HIDD);
        #pragma unroll
        for (int j4 = 0; j4 < HIDD / 4; ++j4) {
            float4 a = pi[j4], b = pj[j4];
            *reinterpret_cast<float4*>(&sH[l][4 * j4]) = make_float4(
                silu_f(a.x + b.x), silu_f(a.y + b.y),
                silu_f(a.z + b.z), silu_f(a.w + b.w));
        }
        sSrc[l] = s;
        sDst[l] = t;
        #pragma unroll
        for (int i = 0; i < 9; ++i) sY[l][i] = edge_rsh[(size_t)e * 9 + i];
    } else {
        // ---- hr = silu(edge_attr @ Wr1 + br1)
        float hr[HIDD];
        #pragma unroll
        for (int j = 0; j < HIDD; ++j) hr[j] = br1[j];
        #pragma unroll 1
        for (int k4 = 0; k4 < RBFD / 4; ++k4) {
            float4 a = reinterpret_cast<const float4*>(edge_attr + (size_t)e * RBFD)[k4];
            const float* wp = Wr1 + (4 * k4) * HIDD;
            #pragma unroll
            for (int j = 0; j < HIDD; ++j) {
                hr[j] = fmaf(a.x, wp[j], hr[j]);
                hr[j] = fmaf(a.y, wp[HIDD + j], hr[j]);
                hr[j] = fmaf(a.z, wp[2 * HIDD + j], hr[j]);
                hr[j] = fmaf(a.w, wp[3 * HIDD + j], hr[j]);
            }
        }
        #pragma unroll
        for (int j4 = 0; j4 < HIDD / 4; ++j4)
            *reinterpret_cast<float4*>(&sH[l][32 + 4 * j4]) = make_float4(
                silu_f(hr[4 * j4 + 0]), silu_f(hr[4 * j4 + 1]),
                silu_f(hr[4 * j4 + 2]), silu_f(hr[4 * j4 + 3]));
    }
    __syncthreads();

    int xcol = h * 64 + l;   // node-feature channel this lane owns
    section_pass<1, 0, 0>     (0 * 128 + xcol, xcol, nf, Ws2, bs2, Wr2, br2, sH, sY, sSrc, sDst);
    section_pass<3, 1, CC>    (1 * 128 + xcol, xcol, nf, Ws2, bs2, Wr2, br2, sH, sY, sSrc, sDst);
    section_pass<5, 4, 4 * CC>(2 * 128 + xcol, xcol, nf, Ws2, bs2, Wr2, br2, sH, sY, sSrc, sDst);
}

// Node-wise linear, 2 nodes per block. (unchanged)
__global__ __launch_bounds__(256) void lin2_kernel(
    const float* __restrict__ W0, const float* __restrict__ b0,
    const float* __restrict__ W1, const float* __restrict__ W2,
    float* __restrict__ out)
{
    __shared__ float sA[2 * MROW];
    int n0 = blockIdx.x * 2;
    const float4* g = reinterpret_cast<const float4*>(g_accu + (size_t)n0 * MROW);
    for (int i = threadIdx.x; i < 2 * MROW / 4; i += 256)
        reinterpret_cast<float4*>(sA)[i] = g[i];
    __syncthreads();

    int d  = threadIdx.x & (CC - 1);
    int nl = threadIdx.x >> 7;
    const float* a = sA + nl * MROW;

    float acc[9];
    #pragma unroll
    for (int m = 0; m < 9; ++m) acc[m] = 0.f;

    #pragma unroll 2
    for (int cc = 0; cc < CC; ++cc) {
        float w0 = W0[cc * CC + d];
        float w1 = W1[cc * CC + d];
        float w2 = W2[cc * CC + d];
        acc[0] = fmaf(a[cc],           w0, acc[0]);
        acc[1] = fmaf(a[CC + cc],      w1, acc[1]);
        acc[2] = fmaf(a[2 * CC + cc],  w1, acc[2]);
        acc[3] = fmaf(a[3 * CC + cc],  w1, acc[3]);
        acc[4] = fmaf(a[4 * CC + cc],  w2, acc[4]);
        acc[5] = fmaf(a[5 * CC + cc],  w2, acc[5]);
        acc[6] = fmaf(a[6 * CC + cc],  w2, acc[6]);
        acc[7] = fmaf(a[7 * CC + cc],  w2, acc[7]);
        acc[8] = fmaf(a[8 * CC + cc],  w2, acc[8]);
    }

    const float inv = 0.08838834764831845f;  // 1/sqrt(128)
    size_t ob = (size_t)(n0 + nl) * MROW;
    out[ob + d] = acc[0] * inv + b0[d];
    #pragma unroll
    for (int m = 0; m < 3; ++m) out[ob + CC + d * 3 + m]     = acc[1 + m] * inv;
    #pragma unroll
    for (int m = 0; m < 5; ++m) out[ob + 4 * CC + d * 5 + m] = acc[4 + m] * inv;
}

extern "C" void kernel_launch(void* const* d_in, const int* in_sizes, int n_in,
                              void* d_out, int out_size, void* d_ws, size_t ws_size,
                              hipStream_t stream)
{
    const float* node_feat  = (const float*)d_in[0];
    const float* edge_attr  = (const float*)d_in[1];
    const float* edge_rsh   = (const float*)d_in[2];
    const int*   edge_index = (const int*)  d_in[3];
    const float* Ws1 = (const float*)d_in[4];
    const float* bs1 = (const float*)d_in[5];
    const float* Ws2 = (const float*)d_in[6];
    const float* bs2 = (const float*)d_in[7];
    const float* Wr1 = (const float*)d_in[8];
    const float* br1 = (const float*)d_in[9];
    const float* Wr2 = (const float*)d_in[10];
    const float* br2 = (const float*)d_in[11];
    const float* W0  = (const float*)d_in[12];
    const float* b0  = (const float*)d_in[13];
    const float* W1  = (const float*)d_in[14];
    const float* W2  = (const float*)d_in[15];
    float* out = (float*)d_out;

    zero_kernel<<<2048, 256, 0, stream>>>();
    hist_kernel<<<EE / 256, 256, 0, stream>>>(edge_index);
    scan_kernel<<<1, 256, 0, stream>>>();
    perm_kernel<<<EE / 256, 256, 0, stream>>>(edge_index);
    proj_kernel<<<(NN + 63) / 64, 64, 0, stream>>>(node_feat, Ws1, bs1);
    fused_kernel<<<EE / 64, 128, 0, stream>>>(
        node_feat, edge_attr, edge_rsh, edge_index,
        Ws2, bs2, Wr1, br1, Wr2, br2);
    lin2_kernel<<<NN / 2, 256, 0, stream>>>(W0, b0, W1, W2, out);
}

// Round 15
// 355.798 us; speedup vs baseline: 1.1265x; 1.1265x over previous
//
#include <hip/hip_runtime.h>
#include <hip/hip_bf16.h>
#include <math.h>

#define NN   10000
#define EE   160000
#define CC   128
#define RBFD 20
#define HIDD 32
#define WND  384
#define MROW 1152   // 9*128 accumulator row: [m=0..8][c=0..127]

// Static device buffers (fully rewritten each call).
__device__ __align__(16) float g_proj[(size_t)NN * 64];   // 2.6 MB: Pi(32,+bs1)|Pj(32)
__device__ __align__(16) float g_accu[(size_t)NN * MROW]; // 46 MB, atomically accumulated
__device__ int g_deg[NN];
__device__ int g_offs[NN + 1];
__device__ int g_rel[EE];
__device__ int g_ord[EE];   // sorted row -> original edge

__device__ __forceinline__ float silu_f(float x) { return x / (1.f + __expf(-x)); }

// Zero g_deg and g_accu in one launch.
__global__ __launch_bounds__(256) void zero_kernel()
{
    int tid = blockIdx.x * 256 + threadIdx.x;
    if (tid < NN) g_deg[tid] = 0;
    float4* p = reinterpret_cast<float4*>(g_accu);
    float4 z = make_float4(0.f, 0.f, 0.f, 0.f);
    int n4 = NN * MROW / 4;
    for (int i = tid; i < n4; i += gridDim.x * 256) p[i] = z;
}

__global__ __launch_bounds__(256) void hist_kernel(const int* __restrict__ edge_index)
{
    int e = blockIdx.x * 256 + threadIdx.x;
    if (e < EE) g_rel[e] = atomicAdd(&g_deg[edge_index[e]], 1);
}

// Blocked scan: 256 threads x 40 items, one block.
__global__ __launch_bounds__(256) void scan_kernel()
{
    __shared__ int sP[256];
    int t = threadIdx.x;
    int lo = t * 40, hi = min(lo + 40, NN);
    int sum = 0;
    for (int i = lo; i < hi; ++i) sum += g_deg[i];
    sP[t] = sum;
    __syncthreads();
    for (int off = 1; off < 256; off <<= 1) {
        int v = (t >= off) ? sP[t - off] : 0;
        __syncthreads();
        sP[t] += v;
        __syncthreads();
    }
    int run = sP[t] - sum;   // exclusive prefix
    if (t == 0) g_offs[0] = 0;
    for (int i = lo; i < hi; ++i) { run += g_deg[i]; g_offs[i + 1] = run; }
}

__global__ __launch_bounds__(256) void perm_kernel(const int* __restrict__ edge_index)
{
    int e = blockIdx.x * 256 + threadIdx.x;
    if (e < EE) g_ord[g_offs[edge_index[e]] + g_rel[e]] = e;
}

// Per-node halves of MLP1: Pi = nf@Ws1[0:128]+bs1, Pj = nf@Ws1[128:256].
__global__ __launch_bounds__(64) void proj_kernel(
    const float* __restrict__ nf,
    const float* __restrict__ Ws1, const float* __restrict__ bs1)
{
    int n = blockIdx.x * 64 + threadIdx.x;
    if (n >= NN) return;
    float Pi[HIDD], Pj[HIDD];
    #pragma unroll
    for (int j = 0; j < HIDD; ++j) { Pi[j] = bs1[j]; Pj[j] = 0.f; }
    const float4* x4 = reinterpret_cast<const float4*>(nf + (size_t)n * CC);
    #pragma unroll 1
    for (int k4 = 0; k4 < CC / 4; ++k4) {
        float4 a = x4[k4];
        const float* wi = Ws1 + (4 * k4) * HIDD;
        const float* wj = Ws1 + (CC + 4 * k4) * HIDD;
        #pragma unroll
        for (int j = 0; j < HIDD; ++j) {
            Pi[j] = fmaf(a.x, wi[j], Pi[j]);
            Pi[j] = fmaf(a.y, wi[HIDD + j], Pi[j]);
            Pi[j] = fmaf(a.z, wi[2 * HIDD + j], Pi[j]);
            Pi[j] = fmaf(a.w, wi[3 * HIDD + j], Pi[j]);
            Pj[j] = fmaf(a.x, wj[j], Pj[j]);
            Pj[j] = fmaf(a.y, wj[HIDD + j], Pj[j]);
            Pj[j] = fmaf(a.z, wj[2 * HIDD + j], Pj[j]);
            Pj[j] = fmaf(a.w, wj[3 * HIDD + j], Pj[j]);
        }
    }
    float* o = g_proj + (size_t)n * 64;
    #pragma unroll
    for (int j = 0; j < HIDD; ++j) { o[j] = Pi[j]; o[HIDD + j] = Pj[j]; }
}

// One 128-col section: lane owns cols (2l, 2l+1); weights pinned in VGPRs via
// asm (compiler cannot rematerialize); streams 64 sorted edges (h broadcast
// b128 from LDS), per-segment register accumulation, wave-coalesced atomics.
template<int K, int YB, int MOFF>
__device__ __forceinline__ void section_pass(
    int sec, int l,
    const float2* __restrict__ nf2,
    const float* __restrict__ Ws2, const float* __restrict__ bs2,
    const float* __restrict__ Wr2, const float* __restrict__ br2,
    const float (*__restrict__ sH)[68], const float (*__restrict__ sY)[9],
    const int* __restrict__ sSrc, const int* __restrict__ sDst)
{
    float W0[HIDD], W1[HIDD], R0[HIDD], R1[HIDD];
    #pragma unroll
    for (int j = 0; j < HIDD; ++j) {
        float2 w = *reinterpret_cast<const float2*>(&Ws2[j * WND + sec * 128 + 2 * l]);
        float2 r = *reinterpret_cast<const float2*>(&Wr2[j * WND + sec * 128 + 2 * l]);
        W0[j] = w.x; W1[j] = w.y; R0[j] = r.x; R1[j] = r.y;
    }
    // Pin: forces one-time materialization into VGPRs (no per-edge reloads).
    #pragma unroll
    for (int j = 0; j < HIDD; ++j)
        asm volatile("" : "+v"(W0[j]), "+v"(W1[j]), "+v"(R0[j]), "+v"(R1[j]));

    float2 bsv = *reinterpret_cast<const float2*>(&bs2[sec * 128 + 2 * l]);
    float2 brv = *reinterpret_cast<const float2*>(&br2[sec * 128 + 2 * l]);

    float racc0[K], racc1[K];
    #pragma unroll
    for (int k = 0; k < K; ++k) { racc0[k] = 0.f; racc1[k] = 0.f; }
    int cur = sSrc[0];
    float2 xjn = nf2[(size_t)sDst[0] * 64 + l];

    #pragma unroll 2
    for (int ee = 0; ee < 64; ++ee) {
        int src = sSrc[ee];                       // broadcast -> wave-uniform
        if (src != cur) {
            float* ab = g_accu + (size_t)cur * MROW + MOFF + 2 * l;
            #pragma unroll
            for (int k = 0; k < K; ++k) {
                unsafeAtomicAdd(ab + k * CC,     racc0[k]);
                unsafeAtomicAdd(ab + k * CC + 1, racc1[k]);
                racc0[k] = 0.f; racc1[k] = 0.f;
            }
            cur = src;
        }
        float2 xj = xjn;
        xjn = nf2[(size_t)sDst[(ee + 1) & 63] * 64 + l];   // prefetch next
        float as0 = bsv.x, as1 = bsv.y, ar0 = brv.x, ar1 = brv.y;
        #pragma unroll
        for (int j4 = 0; j4 < 8; ++j4) {
            float4 hsv = *reinterpret_cast<const float4*>(&sH[ee][4 * j4]);
            float4 hrv = *reinterpret_cast<const float4*>(&sH[ee][32 + 4 * j4]);
            as0 = fmaf(hsv.x, W0[4 * j4 + 0], as0); as1 = fmaf(hsv.x, W1[4 * j4 + 0], as1);
            as0 = fmaf(hsv.y, W0[4 * j4 + 1], as0); as1 = fmaf(hsv.y, W1[4 * j4 + 1], as1);
            as0 = fmaf(hsv.z, W0[4 * j4 + 2], as0); as1 = fmaf(hsv.z, W1[4 * j4 + 2], as1);
            as0 = fmaf(hsv.w, W0[4 * j4 + 3], as0); as1 = fmaf(hsv.w, W1[4 * j4 + 3], as1);
            ar0 = fmaf(hrv.x, R0[4 * j4 + 0], ar0); ar1 = fmaf(hrv.x, R1[4 * j4 + 0], ar1);
            ar0 = fmaf(hrv.y, R0[4 * j4 + 1], ar0); ar1 = fmaf(hrv.y, R1[4 * j4 + 1], ar1);
            ar0 = fmaf(hrv.z, R0[4 * j4 + 2], ar0); ar1 = fmaf(hrv.z, R1[4 * j4 + 2], ar1);
            ar0 = fmaf(hrv.w, R0[4 * j4 + 3], ar0); ar1 = fmaf(hrv.w, R1[4 * j4 + 3], ar1);
        }
        float u0 = as0 * ar0 * xj.x;
        float u1 = as1 * ar1 * xj.y;
        #pragma unroll
        for (int k = 0; k < K; ++k) {
            float yv = sY[ee][YB + k];
            racc0[k] = fmaf(u0, yv, racc0[k]);
            racc1[k] = fmaf(u1, yv, racc1[k]);
        }
    }
    float* ab = g_accu + (size_t)cur * MROW + MOFF + 2 * l;
    #pragma unroll
    for (int k = 0; k < K; ++k) {
        unsafeAtomicAdd(ab + k * CC,     racc0[k]);
        unsafeAtomicAdd(ab + k * CC + 1, racc1[k]);
    }
}

// Fused edge MLP2 + tensor-product message + segment-sum. One wave per block,
// 64 sorted edges per block. Prologue computes MLP1 hiddens (lane=edge) into
// LDS; three section passes (lane=2 cols) run entirely in-register.
__global__ __launch_bounds__(64, 2) void fused_kernel(
    const float* __restrict__ nf,
    const float* __restrict__ edge_attr,
    const float* __restrict__ edge_rsh,
    const int*   __restrict__ edge_index,
    const float* __restrict__ Ws2, const float* __restrict__ bs2,
    const float* __restrict__ Wr1, const float* __restrict__ br1,
    const float* __restrict__ Wr2, const float* __restrict__ br2)
{
    __shared__ float sH[64][68];   // 17.4 KB
    __shared__ float sY[64][9];    // 2.3 KB
    __shared__ int   sSrc[64], sDst[64];

    int l = threadIdx.x;
    int p = blockIdx.x * 64 + l;   // grid exact: EE/64
    int e = g_ord[p];
    int s = edge_index[e];
    int t = edge_index[EE + e];

    // ---- prologue: hs = silu(Pi[s]+Pj[t]), hr = silu(edge_attr@Wr1+br1)
    {
        float hs[HIDD], hr[HIDD];
        const float4* pi = reinterpret_cast<const float4*>(g_proj + (size_t)s * 64);
        const float4* pj = reinterpret_cast<const float4*>(g_proj + (size_t)t * 64 + HIDD);
        #pragma unroll
        for (int j4 = 0; j4 < HIDD / 4; ++j4) {
            float4 a = pi[j4], b = pj[j4];
            hs[4 * j4 + 0] = silu_f(a.x + b.x);
            hs[4 * j4 + 1] = silu_f(a.y + b.y);
            hs[4 * j4 + 2] = silu_f(a.z + b.z);
            hs[4 * j4 + 3] = silu_f(a.w + b.w);
        }
        #pragma unroll
        for (int j = 0; j < HIDD; ++j) hr[j] = br1[j];
        #pragma unroll 1
        for (int k4 = 0; k4 < RBFD / 4; ++k4) {
            float4 a = reinterpret_cast<const float4*>(edge_attr + (size_t)e * RBFD)[k4];
            const float* wp = Wr1 + (4 * k4) * HIDD;
            #pragma unroll
            for (int j = 0; j < HIDD; ++j) {
                hr[j] = fmaf(a.x, wp[j], hr[j]);
                hr[j] = fmaf(a.y, wp[HIDD + j], hr[j]);
                hr[j] = fmaf(a.z, wp[2 * HIDD + j], hr[j]);
                hr[j] = fmaf(a.w, wp[3 * HIDD + j], hr[j]);
            }
        }
        #pragma unroll
        for (int j4 = 0; j4 < HIDD / 4; ++j4) {
            *reinterpret_cast<float4*>(&sH[l][4 * j4]) =
                make_float4(hs[4 * j4], hs[4 * j4 + 1], hs[4 * j4 + 2], hs[4 * j4 + 3]);
            float h0 = silu_f(hr[4 * j4]),     h1 = silu_f(hr[4 * j4 + 1]);
            float h2 = silu_f(hr[4 * j4 + 2]), h3 = silu_f(hr[4 * j4 + 3]);
            *reinterpret_cast<float4*>(&sH[l][32 + 4 * j4]) = make_float4(h0, h1, h2, h3);
        }
        sSrc[l] = s;
        sDst[l] = t;
        #pragma unroll
        for (int i = 0; i < 9; ++i) sY[l][i] = edge_rsh[(size_t)e * 9 + i];
    }
    __syncthreads();

    const float2* nf2 = reinterpret_cast<const float2*>(nf);
    section_pass<1, 0, 0>     (0, l, nf2, Ws2, bs2, Wr2, br2, sH, sY, sSrc, sDst);
    section_pass<3, 1, CC>    (1, l, nf2, Ws2, bs2, Wr2, br2, sH, sY, sSrc, sDst);
    section_pass<5, 4, 4 * CC>(2, l, nf2, Ws2, bs2, Wr2, br2, sH, sY, sSrc, sDst);
}

// Node-wise linear, 2 nodes per block. (unchanged)
__global__ __launch_bounds__(256) void lin2_kernel(
    const float* __restrict__ W0, const float* __restrict__ b0,
    const float* __restrict__ W1, const float* __restrict__ W2,
    float* __restrict__ out)
{
    __shared__ float sA[2 * MROW];
    int n0 = blockIdx.x * 2;
    const float4* g = reinterpret_cast<const float4*>(g_accu + (size_t)n0 * MROW);
    for (int i = threadIdx.x; i < 2 * MROW / 4; i += 256)
        reinterpret_cast<float4*>(sA)[i] = g[i];
    __syncthreads();

    int d  = threadIdx.x & (CC - 1);
    int nl = threadIdx.x >> 7;
    const float* a = sA + nl * MROW;

    float acc[9];
    #pragma unroll
    for (int m = 0; m < 9; ++m) acc[m] = 0.f;

    #pragma unroll 2
    for (int cc = 0; cc < CC; ++cc) {
        float w0 = W0[cc * CC + d];
        float w1 = W1[cc * CC + d];
        float w2 = W2[cc * CC + d];
        acc[0] = fmaf(a[cc],           w0, acc[0]);
        acc[1] = fmaf(a[CC + cc],      w1, acc[1]);
        acc[2] = fmaf(a[2 * CC + cc],  w1, acc[2]);
        acc[3] = fmaf(a[3 * CC + cc],  w1, acc[3]);
        acc[4] = fmaf(a[4 * CC + cc],  w2, acc[4]);
        acc[5] = fmaf(a[5 * CC + cc],  w2, acc[5]);
        acc[6] = fmaf(a[6 * CC + cc],  w2, acc[6]);
        acc[7] = fmaf(a[7 * CC + cc],  w2, acc[7]);
        acc[8] = fmaf(a[8 * CC + cc],  w2, acc[8]);
    }

    const float inv = 0.08838834764831845f;  // 1/sqrt(128)
    size_t ob = (size_t)(n0 + nl) * MROW;
    out[ob + d] = acc[0] * inv + b0[d];
    #pragma unroll
    for (int m = 0; m < 3; ++m) out[ob + CC + d * 3 + m]     = acc[1 + m] * inv;
    #pragma unroll
    for (int m = 0; m < 5; ++m) out[ob + 4 * CC + d * 5 + m] = acc[4 + m] * inv;
}

extern "C" void kernel_launch(void* const* d_in, const int* in_sizes, int n_in,
                              void* d_out, int out_size, void* d_ws, size_t ws_size,
                              hipStream_t stream)
{
    const float* node_feat  = (const float*)d_in[0];
    const float* edge_attr  = (const float*)d_in[1];
    const float* edge_rsh   = (const float*)d_in[2];
    const int*   edge_index = (const int*)  d_in[3];
    const float* Ws1 = (const float*)d_in[4];
    const float* bs1 = (const float*)d_in[5];
    const float* Ws2 = (const float*)d_in[6];
    const float* bs2 = (const float*)d_in[7];
    const float* Wr1 = (const float*)d_in[8];
    const float* br1 = (const float*)d_in[9];
    const float* Wr2 = (const float*)d_in[10];
    const float* br2 = (const float*)d_in[11];
    const float* W0  = (const float*)d_in[12];
    const float* b0  = (const float*)d_in[13];
    const float* W1  = (const float*)d_in[14];
    const float* W2  = (const float*)d_in[15];
    float* out = (float*)d_out;

    zero_kernel<<<2048, 256, 0, stream>>>();
    hist_kernel<<<EE / 256, 256, 0, stream>>>(edge_index);
    scan_kernel<<<1, 256, 0, stream>>>();
    perm_kernel<<<EE / 256, 256, 0, stream>>>(edge_index);
    proj_kernel<<<(NN + 63) / 64, 64, 0, stream>>>(node_feat, Ws1, bs1);
    fused_kernel<<<EE / 64, 64, 0, stream>>>(
        node_feat, edge_attr, edge_rsh, edge_index,
        Ws2, bs2, Wr1, br1, Wr2, br2);
    lin2_kernel<<<NN / 2, 256, 0, stream>>>(W0, b0, W1, W2, out);
}

// Round 16
// 316.744 us; speedup vs baseline: 1.2654x; 1.1233x over previous
//
#include <hip/hip_runtime.h>
#include <hip/hip_bf16.h>
#include <math.h>

#define NN   10000
#define EE   160000
#define CC   128
#define RBFD 20
#define HIDD 32
#define WND  384
#define MROW 1152   // 9*128 accumulator row: [m=0..8][c=0..127]

#if defined(__has_builtin)
#if __has_builtin(__builtin_amdgcn_fdot2)
#define HAS_DOT2 1
#endif
#endif
#ifndef HAS_DOT2
#define HAS_DOT2 0
#endif

typedef _Float16 half2_t __attribute__((ext_vector_type(2)));

__device__ __forceinline__ half2_t u2h(unsigned int u)
{
    union { unsigned int u; half2_t h; } c; c.u = u; return c.h;
}
__device__ __forceinline__ unsigned int pack_h2(float a, float b)
{
    union { half2_t h; unsigned int u; } c;
    c.h.x = (_Float16)a; c.h.y = (_Float16)b; return c.u;
}

// Static device buffers (fully rewritten each call).
__device__ __align__(16) float g_proj[(size_t)NN * 64];   // 2.6 MB: Pi(32,+bs1)|Pj(32)
__device__ __align__(16) float g_accu[(size_t)NN * MROW]; // 46 MB, atomically accumulated
__device__ int g_deg[NN];
__device__ int g_offs[NN + 1];
__device__ int g_rel[EE];
__device__ int g_ord[EE];   // sorted row -> original edge

__device__ __forceinline__ float silu_f(float x) { return x / (1.f + __expf(-x)); }

// Zero g_deg and g_accu in one launch.
__global__ __launch_bounds__(256) void zero_kernel()
{
    int tid = blockIdx.x * 256 + threadIdx.x;
    if (tid < NN) g_deg[tid] = 0;
    float4* p = reinterpret_cast<float4*>(g_accu);
    float4 z = make_float4(0.f, 0.f, 0.f, 0.f);
    int n4 = NN * MROW / 4;
    for (int i = tid; i < n4; i += gridDim.x * 256) p[i] = z;
}

__global__ __launch_bounds__(256) void hist_kernel(const int* __restrict__ edge_index)
{
    int e = blockIdx.x * 256 + threadIdx.x;
    if (e < EE) g_rel[e] = atomicAdd(&g_deg[edge_index[e]], 1);
}

// Blocked scan: 256 threads x 40 items, one block.
__global__ __launch_bounds__(256) void scan_kernel()
{
    __shared__ int sP[256];
    int t = threadIdx.x;
    int lo = t * 40, hi = min(lo + 40, NN);
    int sum = 0;
    for (int i = lo; i < hi; ++i) sum += g_deg[i];
    sP[t] = sum;
    __syncthreads();
    for (int off = 1; off < 256; off <<= 1) {
        int v = (t >= off) ? sP[t - off] : 0;
        __syncthreads();
        sP[t] += v;
        __syncthreads();
    }
    int run = sP[t] - sum;   // exclusive prefix
    if (t == 0) g_offs[0] = 0;
    for (int i = lo; i < hi; ++i) { run += g_deg[i]; g_offs[i + 1] = run; }
}

__global__ __launch_bounds__(256) void perm_kernel(const int* __restrict__ edge_index)
{
    int e = blockIdx.x * 256 + threadIdx.x;
    if (e < EE) g_ord[g_offs[edge_index[e]] + g_rel[e]] = e;
}

// Per-node halves of MLP1: Pi = nf@Ws1[0:128]+bs1, Pj = nf@Ws1[128:256].
__global__ __launch_bounds__(64) void proj_kernel(
    const float* __restrict__ nf,
    const float* __restrict__ Ws1, const float* __restrict__ bs1)
{
    int n = blockIdx.x * 64 + threadIdx.x;
    if (n >= NN) return;
    float Pi[HIDD], Pj[HIDD];
    #pragma unroll
    for (int j = 0; j < HIDD; ++j) { Pi[j] = bs1[j]; Pj[j] = 0.f; }
    const float4* x4 = reinterpret_cast<const float4*>(nf + (size_t)n * CC);
    #pragma unroll 1
    for (int k4 = 0; k4 < CC / 4; ++k4) {
        float4 a = x4[k4];
        const float* wi = Ws1 + (4 * k4) * HIDD;
        const float* wj = Ws1 + (CC + 4 * k4) * HIDD;
        #pragma unroll
        for (int j = 0; j < HIDD; ++j) {
            Pi[j] = fmaf(a.x, wi[j], Pi[j]);
            Pi[j] = fmaf(a.y, wi[HIDD + j], Pi[j]);
            Pi[j] = fmaf(a.z, wi[2 * HIDD + j], Pi[j]);
            Pi[j] = fmaf(a.w, wi[3 * HIDD + j], Pi[j]);
            Pj[j] = fmaf(a.x, wj[j], Pj[j]);
            Pj[j] = fmaf(a.y, wj[HIDD + j], Pj[j]);
            Pj[j] = fmaf(a.z, wj[2 * HIDD + j], Pj[j]);
            Pj[j] = fmaf(a.w, wj[3 * HIDD + j], Pj[j]);
        }
    }
    float* o = g_proj + (size_t)n * 64;
    #pragma unroll
    for (int j = 0; j < HIDD; ++j) { o[j] = Pi[j]; o[HIDD + j] = Pj[j]; }
}

#if HAS_DOT2
// ------------------- f16 dot2 path -------------------
// sH row: 32 u32 = [16 hs-pairs | 16 hr-pairs] packed f16; stride 36 (144B,
// 16B-aligned). Inner reads are broadcast b128 (no conflicts).
template<int K, int YB, int MOFF>
__device__ __forceinline__ void section_pass(
    int sec, int l,
    const float2* __restrict__ nf2,
    const float* __restrict__ Ws2, const float* __restrict__ bs2,
    const float* __restrict__ Wr2, const float* __restrict__ br2,
    const unsigned int (*__restrict__ sH)[36], const float (*__restrict__ sY)[9],
    const int* __restrict__ sSrc, const int* __restrict__ sDst)
{
    unsigned int W0p[16], W1p[16], R0p[16], R1p[16];
    #pragma unroll
    for (int p = 0; p < 16; ++p) {
        int b0 = (2 * p) * WND + sec * 128 + 2 * l;
        int b1 = (2 * p + 1) * WND + sec * 128 + 2 * l;
        W0p[p] = pack_h2(Ws2[b0],     Ws2[b1]);       // col 2l:   j=2p,2p+1
        W1p[p] = pack_h2(Ws2[b0 + 1], Ws2[b1 + 1]);   // col 2l+1
        R0p[p] = pack_h2(Wr2[b0],     Wr2[b1]);
        R1p[p] = pack_h2(Wr2[b0 + 1], Wr2[b1 + 1]);
    }
    #pragma unroll
    for (int p = 0; p < 16; ++p)
        asm volatile("" : "+v"(W0p[p]), "+v"(W1p[p]), "+v"(R0p[p]), "+v"(R1p[p]));

    float2 bsv = *reinterpret_cast<const float2*>(&bs2[sec * 128 + 2 * l]);
    float2 brv = *reinterpret_cast<const float2*>(&br2[sec * 128 + 2 * l]);

    float racc0[K], racc1[K];
    #pragma unroll
    for (int k = 0; k < K; ++k) { racc0[k] = 0.f; racc1[k] = 0.f; }
    int cur = sSrc[0];
    float2 xjn = nf2[(size_t)sDst[0] * 64 + l];

    #pragma unroll 2
    for (int ee = 0; ee < 64; ++ee) {
        int src = sSrc[ee];                       // broadcast -> wave-uniform
        if (src != cur) {
            float* ab = g_accu + (size_t)cur * MROW + MOFF + 2 * l;
            #pragma unroll
            for (int k = 0; k < K; ++k) {
                unsafeAtomicAdd(ab + k * CC,     racc0[k]);
                unsafeAtomicAdd(ab + k * CC + 1, racc1[k]);
                racc0[k] = 0.f; racc1[k] = 0.f;
            }
            cur = src;
        }
        float2 xj = xjn;
        xjn = nf2[(size_t)sDst[(ee + 1) & 63] * 64 + l];   // prefetch next
        const uint4* hp = reinterpret_cast<const uint4*>(&sH[ee][0]);
        float as0 = bsv.x, as1 = bsv.y, ar0 = brv.x, ar1 = brv.y;
        #pragma unroll
        for (int q = 0; q < 4; ++q) {
            uint4 hv = hp[q];       // hs pairs 4q..4q+3 (broadcast)
            uint4 rv = hp[4 + q];   // hr pairs
            as0 = __builtin_amdgcn_fdot2(u2h(hv.x), u2h(W0p[4 * q + 0]), as0, false);
            as1 = __builtin_amdgcn_fdot2(u2h(hv.x), u2h(W1p[4 * q + 0]), as1, false);
            as0 = __builtin_amdgcn_fdot2(u2h(hv.y), u2h(W0p[4 * q + 1]), as0, false);
            as1 = __builtin_amdgcn_fdot2(u2h(hv.y), u2h(W1p[4 * q + 1]), as1, false);
            as0 = __builtin_amdgcn_fdot2(u2h(hv.z), u2h(W0p[4 * q + 2]), as0, false);
            as1 = __builtin_amdgcn_fdot2(u2h(hv.z), u2h(W1p[4 * q + 2]), as1, false);
            as0 = __builtin_amdgcn_fdot2(u2h(hv.w), u2h(W0p[4 * q + 3]), as0, false);
            as1 = __builtin_amdgcn_fdot2(u2h(hv.w), u2h(W1p[4 * q + 3]), as1, false);
            ar0 = __builtin_amdgcn_fdot2(u2h(rv.x), u2h(R0p[4 * q + 0]), ar0, false);
            ar1 = __builtin_amdgcn_fdot2(u2h(rv.x), u2h(R1p[4 * q + 0]), ar1, false);
            ar0 = __builtin_amdgcn_fdot2(u2h(rv.y), u2h(R0p[4 * q + 1]), ar0, false);
            ar1 = __builtin_amdgcn_fdot2(u2h(rv.y), u2h(R1p[4 * q + 1]), ar1, false);
            ar0 = __builtin_amdgcn_fdot2(u2h(rv.z), u2h(R0p[4 * q + 2]), ar0, false);
            ar1 = __builtin_amdgcn_fdot2(u2h(rv.z), u2h(R1p[4 * q + 2]), ar1, false);
            ar0 = __builtin_amdgcn_fdot2(u2h(rv.w), u2h(R0p[4 * q + 3]), ar0, false);
            ar1 = __builtin_amdgcn_fdot2(u2h(rv.w), u2h(R1p[4 * q + 3]), ar1, false);
        }
        float u0 = as0 * ar0 * xj.x;
        float u1 = as1 * ar1 * xj.y;
        #pragma unroll
        for (int k = 0; k < K; ++k) {
            float yv = sY[ee][YB + k];
            racc0[k] = fmaf(u0, yv, racc0[k]);
            racc1[k] = fmaf(u1, yv, racc1[k]);
        }
    }
    float* ab = g_accu + (size_t)cur * MROW + MOFF + 2 * l;
    #pragma unroll
    for (int k = 0; k < K; ++k) {
        unsafeAtomicAdd(ab + k * CC,     racc0[k]);
        unsafeAtomicAdd(ab + k * CC + 1, racc1[k]);
    }
}
#else
// ------------------- fp32 fallback (R15 verbatim) -------------------
template<int K, int YB, int MOFF>
__device__ __forceinline__ void section_pass(
    int sec, int l,
    const float2* __restrict__ nf2,
    const float* __restrict__ Ws2, const float* __restrict__ bs2,
    const float* __restrict__ Wr2, const float* __restrict__ br2,
    const float (*__restrict__ sH)[68], const float (*__restrict__ sY)[9],
    const int* __restrict__ sSrc, const int* __restrict__ sDst)
{
    float W0[HIDD], W1[HIDD], R0[HIDD], R1[HIDD];
    #pragma unroll
    for (int j = 0; j < HIDD; ++j) {
        float2 w = *reinterpret_cast<const float2*>(&Ws2[j * WND + sec * 128 + 2 * l]);
        float2 r = *reinterpret_cast<const float2*>(&Wr2[j * WND + sec * 128 + 2 * l]);
        W0[j] = w.x; W1[j] = w.y; R0[j] = r.x; R1[j] = r.y;
    }
    #pragma unroll
    for (int j = 0; j < HIDD; ++j)
        asm volatile("" : "+v"(W0[j]), "+v"(W1[j]), "+v"(R0[j]), "+v"(R1[j]));

    float2 bsv = *reinterpret_cast<const float2*>(&bs2[sec * 128 + 2 * l]);
    float2 brv = *reinterpret_cast<const float2*>(&br2[sec * 128 + 2 * l]);

    float racc0[K], racc1[K];
    #pragma unroll
    for (int k = 0; k < K; ++k) { racc0[k] = 0.f; racc1[k] = 0.f; }
    int cur = sSrc[0];
    float2 xjn = nf2[(size_t)sDst[0] * 64 + l];

    #pragma unroll 2
    for (int ee = 0; ee < 64; ++ee) {
        int src = sSrc[ee];
        if (src != cur) {
            float* ab = g_accu + (size_t)cur * MROW + MOFF + 2 * l;
            #pragma unroll
            for (int k = 0; k < K; ++k) {
                unsafeAtomicAdd(ab + k * CC,     racc0[k]);
                unsafeAtomicAdd(ab + k * CC + 1, racc1[k]);
                racc0[k] = 0.f; racc1[k] = 0.f;
            }
            cur = src;
        }
        float2 xj = xjn;
        xjn = nf2[(size_t)sDst[(ee + 1) & 63] * 64 + l];
        float as0 = bsv.x, as1 = bsv.y, ar0 = brv.x, ar1 = brv.y;
        #pragma unroll
        for (int j4 = 0; j4 < 8; ++j4) {
            float4 hsv = *reinterpret_cast<const float4*>(&sH[ee][4 * j4]);
            float4 hrv = *reinterpret_cast<const float4*>(&sH[ee][32 + 4 * j4]);
            as0 = fmaf(hsv.x, W0[4 * j4 + 0], as0); as1 = fmaf(hsv.x, W1[4 * j4 + 0], as1);
            as0 = fmaf(hsv.y, W0[4 * j4 + 1], as0); as1 = fmaf(hsv.y, W1[4 * j4 + 1], as1);
            as0 = fmaf(hsv.z, W0[4 * j4 + 2], as0); as1 = fmaf(hsv.z, W1[4 * j4 + 2], as1);
            as0 = fmaf(hsv.w, W0[4 * j4 + 3], as0); as1 = fmaf(hsv.w, W1[4 * j4 + 3], as1);
            ar0 = fmaf(hrv.x, R0[4 * j4 + 0], ar0); ar1 = fmaf(hrv.x, R1[4 * j4 + 0], ar1);
            ar0 = fmaf(hrv.y, R0[4 * j4 + 1], ar0); ar1 = fmaf(hrv.y, R1[4 * j4 + 1], ar1);
            ar0 = fmaf(hrv.z, R0[4 * j4 + 2], ar0); ar1 = fmaf(hrv.z, R1[4 * j4 + 2], ar1);
            ar0 = fmaf(hrv.w, R0[4 * j4 + 3], ar0); ar1 = fmaf(hrv.w, R1[4 * j4 + 3], ar1);
        }
        float u0 = as0 * ar0 * xj.x;
        float u1 = as1 * ar1 * xj.y;
        #pragma unroll
        for (int k = 0; k < K; ++k) {
            float yv = sY[ee][YB + k];
            racc0[k] = fmaf(u0, yv, racc0[k]);
            racc1[k] = fmaf(u1, yv, racc1[k]);
        }
    }
    float* ab = g_accu + (size_t)cur * MROW + MOFF + 2 * l;
    #pragma unroll
    for (int k = 0; k < K; ++k) {
        unsafeAtomicAdd(ab + k * CC,     racc0[k]);
        unsafeAtomicAdd(ab + k * CC + 1, racc1[k]);
    }
}
#endif

// Fused edge MLP2 + tensor-product message + segment-sum. One wave per block,
// 64 sorted edges per block; lane = 2 columns per section pass.
__global__ __launch_bounds__(64, 2) void fused_kernel(
    const float* __restrict__ nf,
    const float* __restrict__ edge_attr,
    const float* __restrict__ edge_rsh,
    const int*   __restrict__ edge_index,
    const float* __restrict__ Ws2, const float* __restrict__ bs2,
    const float* __restrict__ Wr1, const float* __restrict__ br1,
    const float* __restrict__ Wr2, const float* __restrict__ br2)
{
#if HAS_DOT2
    __shared__ unsigned int sH[64][36];   // 9.2 KB packed f16 pairs
#else
    __shared__ float sH[64][68];          // 17.4 KB
#endif
    __shared__ float sY[64][9];           // 2.3 KB
    __shared__ int   sSrc[64], sDst[64];

    int l = threadIdx.x;
    int p = blockIdx.x * 64 + l;   // grid exact: EE/64
    int e = g_ord[p];
    int s = edge_index[e];
    int t = edge_index[EE + e];

    // ---- prologue: hs = silu(Pi[s]+Pj[t]), hr = silu(edge_attr@Wr1+br1)
    {
        float hs[HIDD], hr[HIDD];
        const float4* pi = reinterpret_cast<const float4*>(g_proj + (size_t)s * 64);
        const float4* pj = reinterpret_cast<const float4*>(g_proj + (size_t)t * 64 + HIDD);
        #pragma unroll
        for (int j4 = 0; j4 < HIDD / 4; ++j4) {
            float4 a = pi[j4], b = pj[j4];
            hs[4 * j4 + 0] = silu_f(a.x + b.x);
            hs[4 * j4 + 1] = silu_f(a.y + b.y);
            hs[4 * j4 + 2] = silu_f(a.z + b.z);
            hs[4 * j4 + 3] = silu_f(a.w + b.w);
        }
        #pragma unroll
        for (int j = 0; j < HIDD; ++j) hr[j] = br1[j];
        #pragma unroll 1
        for (int k4 = 0; k4 < RBFD / 4; ++k4) {
            float4 a = reinterpret_cast<const float4*>(edge_attr + (size_t)e * RBFD)[k4];
            const float* wp = Wr1 + (4 * k4) * HIDD;
            #pragma unroll
            for (int j = 0; j < HIDD; ++j) {
                hr[j] = fmaf(a.x, wp[j], hr[j]);
                hr[j] = fmaf(a.y, wp[HIDD + j], hr[j]);
                hr[j] = fmaf(a.z, wp[2 * HIDD + j], hr[j]);
                hr[j] = fmaf(a.w, wp[3 * HIDD + j], hr[j]);
            }
        }
#if HAS_DOT2
        #pragma unroll
        for (int pp = 0; pp < 16; ++pp) {
            sH[l][pp]      = pack_h2(hs[2 * pp], hs[2 * pp + 1]);
            sH[l][16 + pp] = pack_h2(silu_f(hr[2 * pp]), silu_f(hr[2 * pp + 1]));
        }
#else
        #pragma unroll
        for (int j4 = 0; j4 < HIDD / 4; ++j4) {
            *reinterpret_cast<float4*>(&sH[l][4 * j4]) =
                make_float4(hs[4 * j4], hs[4 * j4 + 1], hs[4 * j4 + 2], hs[4 * j4 + 3]);
            float h0 = silu_f(hr[4 * j4]),     h1 = silu_f(hr[4 * j4 + 1]);
            float h2 = silu_f(hr[4 * j4 + 2]), h3 = silu_f(hr[4 * j4 + 3]);
            *reinterpret_cast<float4*>(&sH[l][32 + 4 * j4]) = make_float4(h0, h1, h2, h3);
        }
#endif
        sSrc[l] = s;
        sDst[l] = t;
        #pragma unroll
        for (int i = 0; i < 9; ++i) sY[l][i] = edge_rsh[(size_t)e * 9 + i];
    }
    __syncthreads();

    const float2* nf2 = reinterpret_cast<const float2*>(nf);
    section_pass<1, 0, 0>     (0, l, nf2, Ws2, bs2, Wr2, br2, sH, sY, sSrc, sDst);
    section_pass<3, 1, CC>    (1, l, nf2, Ws2, bs2, Wr2, br2, sH, sY, sSrc, sDst);
    section_pass<5, 4, 4 * CC>(2, l, nf2, Ws2, bs2, Wr2, br2, sH, sY, sSrc, sDst);
}

// Node-wise linear, 2 nodes per block. (unchanged)
__global__ __launch_bounds__(256) void lin2_kernel(
    const float* __restrict__ W0, const float* __restrict__ b0,
    const float* __restrict__ W1, const float* __restrict__ W2,
    float* __restrict__ out)
{
    __shared__ float sA[2 * MROW];
    int n0 = blockIdx.x * 2;
    const float4* g = reinterpret_cast<const float4*>(g_accu + (size_t)n0 * MROW);
    for (int i = threadIdx.x; i < 2 * MROW / 4; i += 256)
        reinterpret_cast<float4*>(sA)[i] = g[i];
    __syncthreads();

    int d  = threadIdx.x & (CC - 1);
    int nl = threadIdx.x >> 7;
    const float* a = sA + nl * MROW;

    float acc[9];
    #pragma unroll
    for (int m = 0; m < 9; ++m) acc[m] = 0.f;

    #pragma unroll 2
    for (int cc = 0; cc < CC; ++cc) {
        float w0 = W0[cc * CC + d];
        float w1 = W1[cc * CC + d];
        float w2 = W2[cc * CC + d];
        acc[0] = fmaf(a[cc],           w0, acc[0]);
        acc[1] = fmaf(a[CC + cc],      w1, acc[1]);
        acc[2] = fmaf(a[2 * CC + cc],  w1, acc[2]);
        acc[3] = fmaf(a[3 * CC + cc],  w1, acc[3]);
        acc[4] = fmaf(a[4 * CC + cc],  w2, acc[4]);
        acc[5] = fmaf(a[5 * CC + cc],  w2, acc[5]);
        acc[6] = fmaf(a[6 * CC + cc],  w2, acc[6]);
        acc[7] = fmaf(a[7 * CC + cc],  w2, acc[7]);
        acc[8] = fmaf(a[8 * CC + cc],  w2, acc[8]);
    }

    const float inv = 0.08838834764831845f;  // 1/sqrt(128)
    size_t ob = (size_t)(n0 + nl) * MROW;
    out[ob + d] = acc[0] * inv + b0[d];
    #pragma unroll
    for (int m = 0; m < 3; ++m) out[ob + CC + d * 3 + m]     = acc[1 + m] * inv;
    #pragma unroll
    for (int m = 0; m < 5; ++m) out[ob + 4 * CC + d * 5 + m] = acc[4 + m] * inv;
}

extern "C" void kernel_launch(void* const* d_in, const int* in_sizes, int n_in,
                              void* d_out, int out_size, void* d_ws, size_t ws_size,
                              hipStream_t stream)
{
    const float* node_feat  = (const float*)d_in[0];
    const float* edge_attr  = (const float*)d_in[1];
    const float* edge_rsh   = (const float*)d_in[2];
    const int*   edge_index = (const int*)  d_in[3];
    const float* Ws1 = (const float*)d_in[4];
    const float* bs1 = (const float*)d_in[5];
    const float* Ws2 = (const float*)d_in[6];
    const float* bs2 = (const float*)d_in[7];
    const float* Wr1 = (const float*)d_in[8];
    const float* br1 = (const float*)d_in[9];
    const float* Wr2 = (const float*)d_in[10];
    const float* br2 = (const float*)d_in[11];
    const float* W0  = (const float*)d_in[12];
    const float* b0  = (const float*)d_in[13];
    const float* W1  = (const float*)d_in[14];
    const float* W2  = (const float*)d_in[15];
    float* out = (float*)d_out;

    zero_kernel<<<2048, 256, 0, stream>>>();
    hist_kernel<<<EE / 256, 256, 0, stream>>>(edge_index);
    scan_kernel<<<1, 256, 0, stream>>>();
    perm_kernel<<<EE / 256, 256, 0, stream>>>(edge_index);
    proj_kernel<<<(NN + 63) / 64, 64, 0, stream>>>(node_feat, Ws1, bs1);
    fused_kernel<<<EE / 64, 64, 0, stream>>>(
        node_feat, edge_attr, edge_rsh, edge_index,
        Ws2, bs2, Wr1, br1, Wr2, br2);
    lin2_kernel<<<NN / 2, 256, 0, stream>>>(W0, b0, W1, W2, out);
}